// Round 1
// baseline (84.399 us; speedup 1.0000x reference)
//
#include <hip/hip_runtime.h>

#define N_CLASSES 21
#define SMOOTH 1e-5f
#define FIX_SCALE 16777216.0f        // 2^24
#define INV_FIX_SCALE (1.0f / 16777216.0f)

// Pack (count, fixed-point sum) into one u64: count in bits [48,64), sum<<24 in [0,48).
// Per-block bounds: <=16384 elems/class -> count < 2^16; sum_fixed < 2^48. No overflow.

__global__ __launch_bounds__(256) void mse_partial(
    const float* __restrict__ outv,
    const int*   __restrict__ gt,
    float*        __restrict__ gsum,
    unsigned int* __restrict__ gcnt,
    int n, int n4)
{
    __shared__ unsigned long long s_acc[N_CLASSES];
    const int tid = threadIdx.x;
    if (tid < N_CLASSES) s_acc[tid] = 0ull;
    __syncthreads();

    const float4* __restrict__ out4 = (const float4*)outv;
    const int4*   __restrict__ gt4  = (const int4*)gt;
    const int stride = gridDim.x * blockDim.x;

    for (int i = blockIdx.x * blockDim.x + tid; i < n4; i += stride) {
        float4 o = out4[i];
        int4   g = gt4[i];

        float d0 = (float)g.x - o.x;
        float d1 = (float)g.y - o.y;
        float d2 = (float)g.z - o.z;
        float d3 = (float)g.w - o.w;

        atomicAdd(&s_acc[g.x], (1ull << 48) + (unsigned long long)(d0 * d0 * FIX_SCALE));
        atomicAdd(&s_acc[g.y], (1ull << 48) + (unsigned long long)(d1 * d1 * FIX_SCALE));
        atomicAdd(&s_acc[g.z], (1ull << 48) + (unsigned long long)(d2 * d2 * FIX_SCALE));
        atomicAdd(&s_acc[g.w], (1ull << 48) + (unsigned long long)(d3 * d3 * FIX_SCALE));
    }

    // Tail (n not divisible by 4) — handled by block 0 only.
    if (blockIdx.x == 0) {
        for (int i = n4 * 4 + tid; i < n; i += blockDim.x) {
            float d = (float)gt[i] - outv[i];
            atomicAdd(&s_acc[gt[i]], (1ull << 48) + (unsigned long long)(d * d * FIX_SCALE));
        }
    }

    __syncthreads();
    if (tid < N_CLASSES) {
        unsigned long long v = s_acc[tid];
        unsigned int cnt = (unsigned int)(v >> 48);
        if (cnt) {
            float sum = (float)(v & 0xFFFFFFFFFFFFull) * INV_FIX_SCALE;
            atomicAdd(&gsum[tid], sum);
            atomicAdd(&gcnt[tid], cnt);
        }
    }
}

__global__ void mse_finalize(const float* __restrict__ gsum,
                             const unsigned int* __restrict__ gcnt,
                             float* __restrict__ d_o, int n_out)
{
    int c = threadIdx.x;
    if (c < n_out) {
        float cnt = fmaxf((float)gcnt[c], SMOOTH);
        d_o[c] = gsum[c] / cnt;
    }
}

extern "C" void kernel_launch(void* const* d_in, const int* in_sizes, int n_in,
                              void* d_out, int out_size, void* d_ws, size_t ws_size,
                              hipStream_t stream)
{
    const float* outputs = (const float*)d_in[0];
    const int*   gt      = (const int*)d_in[1];
    float*       d_o     = (float*)d_out;

    const int n  = in_sizes[0];
    const int n4 = n / 4;

    float*        gsum = (float*)d_ws;
    unsigned int* gcnt = (unsigned int*)((char*)d_ws + 128);

    // Zero the 21 sums + 21 counts (deterministic each call; graph-capture safe).
    hipMemsetAsync(d_ws, 0, 256, stream);

    const int blocks = 2048;
    mse_partial<<<blocks, 256, 0, stream>>>(outputs, gt, gsum, gcnt, n, n4);
    mse_finalize<<<1, 64, 0, stream>>>(gsum, gcnt, d_o, out_size);
}

// Round 2
// 80.282 us; speedup vs baseline: 1.0513x; 1.0513x over previous
//
#include <hip/hip_runtime.h>

#define N_CLASSES 21
#define SMOOTH 1e-5f
#define FIX_SCALE 16777216.0f        // 2^24
#define INV_FIX_SCALE (1.0f / 16777216.0f)
#define NWAVES 4
#define SLOT_PAD 33                  // 32 slots + 1 pad (pad doubles as stage-1 scratch)

// Pack (count, fixed-point sum) into one u64: count in bits [48,64), sum<<24 in [0,48).
// Per-slot bounds: <=~256 elems -> count << 2^16; sum_fixed << 2^48. No overflow.
// Privatized per (wave, lane&31): same-address atomic collisions only for lane pairs
// (l, l+32) with equal class (p ~ 1/21) -> ds_add_u64 runs at pipe throughput.

__global__ __launch_bounds__(256) void mse_partial(
    const float* __restrict__ outv,
    const int*   __restrict__ gt,
    float*        __restrict__ gsum,
    unsigned int* __restrict__ gcnt,
    int n, int n4)
{
    __shared__ unsigned long long s_acc[NWAVES][N_CLASSES][SLOT_PAD];
    const int tid  = threadIdx.x;
    const int w    = tid >> 6;
    const int slot = tid & 31;

    unsigned long long* flat = &s_acc[0][0][0];
    for (int i = tid; i < NWAVES * N_CLASSES * SLOT_PAD; i += 256)
        flat[i] = 0ull;
    __syncthreads();

    const float4* __restrict__ out4 = (const float4*)outv;
    const int4*   __restrict__ gt4  = (const int4*)gt;
    const int stride = gridDim.x * blockDim.x;

    for (int i = blockIdx.x * blockDim.x + tid; i < n4; i += stride) {
        float4 o = out4[i];
        int4   g = gt4[i];

        float d0 = (float)g.x - o.x;
        float d1 = (float)g.y - o.y;
        float d2 = (float)g.z - o.z;
        float d3 = (float)g.w - o.w;

        atomicAdd(&s_acc[w][g.x][slot], (1ull << 48) + (unsigned long long)(d0 * d0 * FIX_SCALE));
        atomicAdd(&s_acc[w][g.y][slot], (1ull << 48) + (unsigned long long)(d1 * d1 * FIX_SCALE));
        atomicAdd(&s_acc[w][g.z][slot], (1ull << 48) + (unsigned long long)(d2 * d2 * FIX_SCALE));
        atomicAdd(&s_acc[w][g.w][slot], (1ull << 48) + (unsigned long long)(d3 * d3 * FIX_SCALE));
    }

    // Tail (n not divisible by 4) — block 0 only.
    if (blockIdx.x == 0) {
        for (int i = n4 * 4 + tid; i < n; i += blockDim.x) {
            float d = (float)gt[i] - outv[i];
            atomicAdd(&s_acc[w][gt[i]][slot], (1ull << 48) + (unsigned long long)(d * d * FIX_SCALE));
        }
    }

    __syncthreads();

    // Stage 1: 84 threads, each sums one (wave, class) row of 32 slots into the pad slot.
    if (tid < NWAVES * N_CLASSES) {
        const int ww = tid / N_CLASSES;
        const int c  = tid % N_CLASSES;
        unsigned long long s = 0ull;
        #pragma unroll
        for (int j = 0; j < 32; ++j) s += s_acc[ww][c][j];
        s_acc[ww][c][32] = s;
    }
    __syncthreads();

    // Stage 2: 21 threads fold the 4 wave partials, then one global atomic pair each.
    if (tid < N_CLASSES) {
        unsigned long long v = s_acc[0][tid][32] + s_acc[1][tid][32]
                             + s_acc[2][tid][32] + s_acc[3][tid][32];
        unsigned int cnt = (unsigned int)(v >> 48);
        if (cnt) {
            float sum = (float)(v & 0xFFFFFFFFFFFFull) * INV_FIX_SCALE;
            atomicAdd(&gsum[tid], sum);
            atomicAdd(&gcnt[tid], cnt);
        }
    }
}

__global__ void mse_finalize(const float* __restrict__ gsum,
                             const unsigned int* __restrict__ gcnt,
                             float* __restrict__ d_o, int n_out)
{
    int c = threadIdx.x;
    if (c < n_out) {
        float cnt = fmaxf((float)gcnt[c], SMOOTH);
        d_o[c] = gsum[c] / cnt;
    }
}

extern "C" void kernel_launch(void* const* d_in, const int* in_sizes, int n_in,
                              void* d_out, int out_size, void* d_ws, size_t ws_size,
                              hipStream_t stream)
{
    const float* outputs = (const float*)d_in[0];
    const int*   gt      = (const int*)d_in[1];
    float*       d_o     = (float*)d_out;

    const int n  = in_sizes[0];
    const int n4 = n / 4;

    float*        gsum = (float*)d_ws;
    unsigned int* gcnt = (unsigned int*)((char*)d_ws + 128);

    // Zero the 21 sums + 21 counts (deterministic each call; graph-capture safe).
    hipMemsetAsync(d_ws, 0, 256, stream);

    const int blocks = 1792;  // 7 blocks/CU x 256 CUs (LDS 22.2 KB/block -> 7 resident)
    mse_partial<<<blocks, 256, 0, stream>>>(outputs, gt, gsum, gcnt, n, n4);
    mse_finalize<<<1, 64, 0, stream>>>(gsum, gcnt, d_o, out_size);
}